// Round 9
// baseline (248.037 us; speedup 1.0000x reference)
//
#include <hip/hip_runtime.h>

#define NN 50000
#define NE 800000
#define DIM 128
#define NG 64
#define ETOT (NE + NN)
#define NEG_SLOPE 0.2f
#define PB 200          // pooling blocks; chunk = 250 nodes
#define MAXLG 8         // local graph slots per block
#define NSH 8           // dst shards (== XCDs)
#define SHW ((NN + NSH - 1) / NSH)   // 6250 nodes per shard
#define NB_SCAN ((NN + 255) / 256)   // 196
#define CAP 2048        // staged edges per 64-node aggregation block (mean 1088, +30 sigma)

typedef unsigned int uint32;
typedef unsigned short ushort;
typedef short bf16x8 __attribute__((ext_vector_type(8)));
typedef float f32x4 __attribute__((ext_vector_type(4)));

static __device__ __forceinline__ uint32 f2bf_pack(float lo, float hi) {
  uint32 a = __float_as_uint(lo), b = __float_as_uint(hi);
  a = (a + 0x7fffu + ((a >> 16) & 1u)) >> 16;          // RNE
  b = (b + 0x7fffu + ((b >> 16) & 1u)) >> 16;
  return a | (b << 16);
}
static __device__ __forceinline__ ushort f2bf1(float x) {
  uint32 a = __float_as_uint(x);
  a = (a + 0x7fffu + ((a >> 16) & 1u)) >> 16;
  return (ushort)a;
}
static __device__ __forceinline__ float bf_lo(uint32 u) { return __uint_as_float(u << 16); }
static __device__ __forceinline__ float bf_hi(uint32 u) { return __uint_as_float(u & 0xffff0000u); }

// ============================ init + weight prep (fused) ============================

__global__ __launch_bounds__(256) void k_init(const float* __restrict__ W1, const float* __restrict__ W2,
                                              ushort* __restrict__ wt1, ushort* __restrict__ wt2,
                                              int* deg, int* fill, float* pooled, float* cnt) {
  int i = blockIdx.x * 256 + threadIdx.x;
  if (i < NN) { deg[i] = 1; fill[i] = 1; }          // 1 = self-loop
  if (i < NG * DIM) pooled[i] = 0.f;
  if (i < NG) cnt[i] = 0.f;
  if (i < DIM * DIM) {                              // W^T bf16 rows (contiguous k) for MFMA B-frags
    int n = i >> 7, k = i & 127;
    wt1[i] = f2bf1(W1[k * DIM + n]);
    wt2[i] = f2bf1(W2[k * DIM + n]);
  }
}

__global__ __launch_bounds__(256) void k_count(const int* __restrict__ dst, int* __restrict__ deg) {
  int e = blockIdx.x * 256 + threadIdx.x;
  if (e < NE) atomicAdd(&deg[dst[e]], 1);
}

// ---- 3-phase multi-block inclusive scan: offs[i+1] = sum(deg[0..i]) ----

__global__ __launch_bounds__(256) void k_scan1(const int* __restrict__ deg, int* __restrict__ offs,
                                               int* __restrict__ bsum) {
  __shared__ int ws[4];
  const int i = blockIdx.x * 256 + threadIdx.x;
  const int lane = threadIdx.x & 63, wid = threadIdx.x >> 6;
  int x = (i < NN) ? deg[i] : 0;
#pragma unroll
  for (int off = 1; off < 64; off <<= 1) {
    int t = __shfl_up(x, off, 64);
    if (lane >= off) x += t;
  }
  if (lane == 63) ws[wid] = x;
  __syncthreads();
  int pre = 0;
#pragma unroll
  for (int j = 0; j < 3; ++j) if (j < wid) pre += ws[j];
  x += pre;
  if (i < NN) offs[i + 1] = x;
  if (threadIdx.x == 255) bsum[blockIdx.x] = x;
}

__global__ __launch_bounds__(256) void k_scan2(const int* __restrict__ bsum, int* __restrict__ bpre) {
  __shared__ int ws[4];
  const int b = threadIdx.x;
  const int lane = b & 63, wid = b >> 6;
  int v = (b < NB_SCAN) ? bsum[b] : 0;
  int x = v;
#pragma unroll
  for (int off = 1; off < 64; off <<= 1) {
    int t = __shfl_up(x, off, 64);
    if (lane >= off) x += t;
  }
  if (lane == 63) ws[wid] = x;
  __syncthreads();
  int pre = 0;
#pragma unroll
  for (int j = 0; j < 3; ++j) if (j < wid) pre += ws[j];
  x += pre;
  if (b < NB_SCAN) bpre[b] = x - v;     // exclusive prefix of block totals
}

// scan3 + self-loop placement fused: slot offs[i] == offs[i+1] - deg[i]
__global__ __launch_bounds__(256) void k_scan3(int* __restrict__ offs, const int* __restrict__ bpre,
                                               const int* __restrict__ deg, int* __restrict__ csr) {
  const int i = blockIdx.x * 256 + threadIdx.x;
  if (i < NN) {
    int v = offs[i + 1] + bpre[blockIdx.x];
    offs[i + 1] = v;
    csr[v - deg[i]] = i;                // slot 0 of each segment = self-loop
  }
  if (i == 0) offs[0] = 0;
}

// XCD-sharded scatter (round-5 notes): each csr line dirtied by one XCD only.
__global__ __launch_bounds__(256) void k_scatter(const int* __restrict__ src, const int* __restrict__ dst,
                                                 const int* __restrict__ offs, int* __restrict__ fill,
                                                 int* __restrict__ csr) {
  const int r = blockIdx.x & (NSH - 1);
  const int bi = blockIdx.x >> 3;
  const int nb = gridDim.x >> 3;
  const int lo = r * SHW, hi = min(lo + SHW, NN);
  for (int e = bi * 256 + threadIdx.x; e < NE; e += nb * 256) {
    int d = dst[e];
    if (d >= lo && d < hi) {
      int p = offs[d] + atomicAdd(&fill[d], 1);
      csr[p] = src[e];
    }
  }
}

// ============== MFMA GEMM: H16 = bf16(X @ W), alpha fused; A16=1 -> X is bf16-packed ==============

template <int A16>
__global__ __launch_bounds__(256) void k_mm(const void* __restrict__ Xv, const ushort* __restrict__ WT,
                                            const float* __restrict__ a_s, const float* __restrict__ a_d,
                                            uint32* __restrict__ H16,
                                            float* __restrict__ alpha_s, float* __restrict__ alpha_d, int n) {
  __shared__ __align__(16) ushort sWT[DIM * DIM];   // 32 KB
  __shared__ __align__(16) ushort sA[64 * DIM];     // 16 KB
  const int tid = threadIdx.x;
  const int row0 = blockIdx.x * 64;

  {  // stage W^T -> LDS (swizzled)
    const int nr = tid >> 1, h2 = tid & 1;
    const uint4* wp = (const uint4*)(WT + nr * DIM + h2 * 64);
#pragma unroll
    for (int i = 0; i < 8; ++i) {
      uint4 v = wp[i];
      int byte = nr * 256 + (((h2 * 128 + i * 16)) ^ ((nr & 7) << 4));
      *(uint4*)((char*)sWT + byte) = v;
    }
  }
  {  // stage A -> LDS (bf16, swizzled)
    const int r = tid >> 2, q = tid & 3;
    int rg = row0 + r; if (rg > n - 1) rg = n - 1;
    if (A16) {
      const uint4* xp = (const uint4*)((const uint32*)Xv + (size_t)rg * 64 + q * 16);
#pragma unroll
      for (int i = 0; i < 4; ++i) {
        uint4 pk = xp[i];
        int byte = r * 256 + ((q * 64 + i * 16) ^ ((r & 7) << 4));
        *(uint4*)((char*)sA + byte) = pk;
      }
    } else {
      const float4* xp = (const float4*)((const float*)Xv + (size_t)rg * DIM + q * 32);
#pragma unroll
      for (int i = 0; i < 4; ++i) {
        float4 v0 = xp[2 * i], v1 = xp[2 * i + 1];
        uint4 pk = make_uint4(f2bf_pack(v0.x, v0.y), f2bf_pack(v0.z, v0.w),
                              f2bf_pack(v1.x, v1.y), f2bf_pack(v1.z, v1.w));
        int byte = r * 256 + ((q * 64 + i * 16) ^ ((r & 7) << 4));
        *(uint4*)((char*)sA + byte) = pk;
      }
    }
  }
  __syncthreads();

  const int l = tid & 63, wv = tid >> 6;
  const int jr = l & 15, g = l >> 4;
  const int m0 = wv * 16;
  f32x4 acc[8];
#pragma unroll
  for (int nt = 0; nt < 8; ++nt) acc[nt] = (f32x4){0.f, 0.f, 0.f, 0.f};

  const int ra = m0 + jr;
  const int abase = ra * 256, aswz = (ra & 7) << 4;
  const int bswz = (jr & 7) << 4;
#pragma unroll
  for (int kk = 0; kk < 4; ++kk) {
    const int kb = kk * 64 + g * 16;
    bf16x8 af = *(const bf16x8*)((const char*)sA + abase + (kb ^ aswz));
#pragma unroll
    for (int nt = 0; nt < 8; ++nt) {
      bf16x8 bfg = *(const bf16x8*)((const char*)sWT + (nt * 16 + jr) * 256 + (kb ^ bswz));
      acc[nt] = __builtin_amdgcn_mfma_f32_16x16x32_bf16(af, bfg, acc[nt], 0, 0, 0);
    }
  }

  // fused alpha from f32 accumulators: row = m0 + g*4 + j, col = nt*16 + jr
  float asv[8], adv[8];
#pragma unroll
  for (int nt = 0; nt < 8; ++nt) { asv[nt] = a_s[nt * 16 + jr]; adv[nt] = a_d[nt * 16 + jr]; }
#pragma unroll
  for (int j = 0; j < 4; ++j) {
    float ps = 0.f, pd = 0.f;
#pragma unroll
    for (int nt = 0; nt < 8; ++nt) {
      ps = fmaf(acc[nt][j], asv[nt], ps);
      pd = fmaf(acc[nt][j], adv[nt], pd);
    }
#pragma unroll
    for (int off = 1; off < 16; off <<= 1) {
      ps += __shfl_xor(ps, off, 64);
      pd += __shfl_xor(pd, off, 64);
    }
    int r = row0 + m0 + g * 4 + j;
    if (jr == 0 && r < n) { alpha_s[r] = ps; alpha_d[r] = pd; }
  }

  // bf16 output bounce through this wave's own sA rows, then coalesced stores
  ushort* sOut = sA;
#pragma unroll
  for (int nt = 0; nt < 8; ++nt)
#pragma unroll
    for (int j = 0; j < 4; ++j)
      sOut[(m0 + g * 4 + j) * DIM + nt * 16 + jr] = f2bf1(acc[nt][j]);
#pragma unroll
  for (int i = 0; i < 4; ++i) {
    int r = row0 + m0 + (l >> 4) + i * 4;
    uint4 v = *(const uint4*)((const char*)sOut + m0 * 256 + l * 16 + i * 1024);
    if (r < n) *(uint4*)(H16 + (size_t)(row0 + m0) * 64 + l * 4 + i * 256) = v;
  }
}

// ============ fused edge-softmax + aggregation v3: LDS-staged, 64 nodes/block ============
// Phase 1a: edge-parallel stage of (src, alpha_s[src]) -> LDS (coalesced csr, high-ILP gather).
// Phase 1b: per-node softmax entirely in LDS (16-lane groups), ex overwritten in place.
// Phase 2:  wave-per-node feature gather; (src, ex) come from uniform-address LDS
//           broadcast reads (no ds_bpermute, no lockstep pairing), 4-deep unroll.

template <int STORE16>
__global__ __launch_bounds__(256) void k_sma(const int* __restrict__ offs, const int* __restrict__ csr,
                                             const float* __restrict__ alpha_s, const float* __restrict__ alpha_d,
                                             const uint32* __restrict__ H16, const float* __restrict__ bias,
                                             float* __restrict__ out, uint32* __restrict__ out16) {
  __shared__ int s_src[CAP];
  __shared__ float s_ex[CAP];
  __shared__ float s_inv[64];
  __shared__ int s_off[65];
  const int tid = threadIdx.x;
  const int n0 = blockIdx.x * 64;
  const int nn = min(64, NN - n0);
  if (tid <= nn) s_off[tid] = offs[n0 + tid];
  __syncthreads();
  const int ebeg = s_off[0];
  const int nE = s_off[nn] - ebeg;
  const int l = tid & 63, wv = tid >> 6;
  const float2 bb = *(const float2*)(bias + 2 * l);

  if (nE <= CAP) {
    // ---- phase 1a ----
    for (int e = tid; e < nE; e += 256) {
      int sv = csr[ebeg + e];
      s_src[e] = sv;
      s_ex[e] = alpha_s[sv];
    }
    __syncthreads();
    // ---- phase 1b ----
    {
      const int g = tid >> 4, l16 = tid & 15;
      for (int i = g; i < nn; i += 16) {
        const float ad = alpha_d[n0 + i];
        const int jb = s_off[i] - ebeg, je = s_off[i + 1] - ebeg;
        float m = -1e30f;
        for (int j = jb + l16; j < je; j += 16) {
          float sc = s_ex[j] + ad;
          sc = sc > 0.f ? sc : NEG_SLOPE * sc;
          m = fmaxf(m, sc);
        }
#pragma unroll
        for (int off = 1; off < 16; off <<= 1) m = fmaxf(m, __shfl_xor(m, off, 64));
        float ssum = 0.f;
        for (int j = jb + l16; j < je; j += 16) {
          float sc = s_ex[j] + ad;
          sc = sc > 0.f ? sc : NEG_SLOPE * sc;
          float ex = __expf(sc - m);
          s_ex[j] = ex;
          ssum += ex;
        }
#pragma unroll
        for (int off = 1; off < 16; off <<= 1) ssum += __shfl_xor(ssum, off, 64);
        if (l16 == 0) s_inv[i] = 1.f / (ssum + 1e-16f);
      }
    }
    __syncthreads();
    // ---- phase 2 ----
    for (int i = wv; i < nn; i += 4) {
      const int jb = s_off[i] - ebeg, je = s_off[i + 1] - ebeg;
      float ax = 0.f, ay = 0.f;
      int j = jb;
      for (; j + 3 < je; j += 4) {
        int s0 = s_src[j], s1 = s_src[j + 1], s2 = s_src[j + 2], s3 = s_src[j + 3];
        float c0 = s_ex[j], c1 = s_ex[j + 1], c2 = s_ex[j + 2], c3 = s_ex[j + 3];
        uint32 v0 = H16[(size_t)s0 * 64 + l];
        uint32 v1 = H16[(size_t)s1 * 64 + l];
        uint32 v2 = H16[(size_t)s2 * 64 + l];
        uint32 v3 = H16[(size_t)s3 * 64 + l];
        ax = fmaf(c0, bf_lo(v0), ax); ay = fmaf(c0, bf_hi(v0), ay);
        ax = fmaf(c1, bf_lo(v1), ax); ay = fmaf(c1, bf_hi(v1), ay);
        ax = fmaf(c2, bf_lo(v2), ax); ay = fmaf(c2, bf_hi(v2), ay);
        ax = fmaf(c3, bf_lo(v3), ax); ay = fmaf(c3, bf_hi(v3), ay);
      }
      for (; j < je; ++j) {
        int s0 = s_src[j]; float c0 = s_ex[j];
        uint32 v0 = H16[(size_t)s0 * 64 + l];
        ax = fmaf(c0, bf_lo(v0), ax); ay = fmaf(c0, bf_hi(v0), ay);
      }
      const float inv = s_inv[i];
      const float ox = ax * inv + bb.x, oy = ay * inv + bb.y;
      const int node = n0 + i;
      if (STORE16) out16[(size_t)node * 64 + l] = f2bf_pack(ox, oy);
      else *(float2*)(out + (size_t)node * DIM + 2 * l) = make_float2(ox, oy);
    }
  } else {
    // ---- fallback: direct per-node two-pass (rare: block edges > CAP) ----
    for (int i = wv; i < nn; i += 4) {
      const int node = n0 + i;
      const int bg = offs[node], eg = offs[node + 1];
      const float ad = alpha_d[node];
      float m = -1e30f;
      for (int jj = bg + l; jj < eg; jj += 64) {
        float sc = alpha_s[csr[jj]] + ad;
        sc = sc > 0.f ? sc : NEG_SLOPE * sc;
        m = fmaxf(m, sc);
      }
#pragma unroll
      for (int off = 1; off < 64; off <<= 1) m = fmaxf(m, __shfl_xor(m, off, 64));
      float ax = 0.f, ay = 0.f, ssum = 0.f;
      for (int base = bg; base < eg; base += 64) {
        int cnt = min(64, eg - base);
        int sv = 0; float ex = 0.f;
        if (l < cnt) {
          sv = csr[base + l];
          float sc = alpha_s[sv] + ad;
          sc = sc > 0.f ? sc : NEG_SLOPE * sc;
          ex = __expf(sc - m);
        }
        ssum += ex;
        for (int jj = 0; jj < cnt; ++jj) {
          int s0 = __shfl(sv, jj, 64); float c0 = __shfl(ex, jj, 64);
          uint32 v0 = H16[(size_t)s0 * 64 + l];
          ax = fmaf(c0, bf_lo(v0), ax); ay = fmaf(c0, bf_hi(v0), ay);
        }
      }
#pragma unroll
      for (int off = 1; off < 64; off <<= 1) ssum += __shfl_xor(ssum, off, 64);
      const float inv = 1.f / (ssum + 1e-16f);
      const float ox = ax * inv + bb.x, oy = ay * inv + bb.y;
      if (STORE16) out16[(size_t)node * 64 + l] = f2bf_pack(ox, oy);
      else *(float2*)(out + (size_t)node * DIM + 2 * l) = make_float2(ox, oy);
    }
  }
}

// ============================ global mean pool (hierarchical, batch sorted) ============================

__global__ __launch_bounds__(256) void k_pool_partial(const float* __restrict__ feats,
                                                      const int* __restrict__ batch,
                                                      float* __restrict__ pooled, float* __restrict__ cnt) {
  __shared__ float acc[4][MAXLG][DIM];
  __shared__ float lcnt[4][MAXLG];
  const int tid = threadIdx.x;
  const int wid = tid >> 6, l = tid & 63;
  for (int i = tid; i < 4 * MAXLG * DIM; i += 256) ((float*)acc)[i] = 0.f;
  if (tid < 4 * MAXLG) ((float*)lcnt)[tid] = 0.f;
  __syncthreads();

  const int chunk = (NN + PB - 1) / PB;
  const int beg = blockIdx.x * chunk;
  const int end = min(beg + chunk, NN);
  const int g0 = (beg < NN) ? batch[beg] : 0;

  for (int node = beg + wid; node < end; node += 4) {
    int lg = batch[node] - g0;
    float2 v = *(const float2*)(feats + (size_t)node * DIM + 2 * l);
    if (lg < MAXLG) {
      acc[wid][lg][2 * l] += v.x;
      acc[wid][lg][2 * l + 1] += v.y;
      if (l == 0) lcnt[wid][lg] += 1.f;
    } else {
      atomicAdd(&pooled[(g0 + lg) * DIM + 2 * l], v.x);
      atomicAdd(&pooled[(g0 + lg) * DIM + 2 * l + 1], v.y);
      if (l == 0) atomicAdd(&cnt[g0 + lg], 1.f);
    }
  }
  __syncthreads();

  for (int i = tid; i < MAXLG * DIM; i += 256) {
    int lg = i >> 7, d = i & (DIM - 1);
    float s = acc[0][lg][d] + acc[1][lg][d] + acc[2][lg][d] + acc[3][lg][d];
    if (s != 0.f) atomicAdd(&pooled[(g0 + lg) * DIM + d], s);
  }
  if (tid < MAXLG) {
    float s = lcnt[0][tid] + lcnt[1][tid] + lcnt[2][tid] + lcnt[3][tid];
    if (s != 0.f) atomicAdd(&cnt[g0 + tid], s);
  }
}

__global__ __launch_bounds__(256) void k_pool_norm(float* pooled, const float* __restrict__ cnt) {
  int i = blockIdx.x * 256 + threadIdx.x;
  if (i < NG * DIM) pooled[i] /= fmaxf(cnt[i >> 7], 1.f);
}

// ============================ launch ============================

static inline size_t pad256(size_t x) { return (x + 255) & ~(size_t)255; }

extern "C" void kernel_launch(void* const* d_in, const int* in_sizes, int n_in,
                              void* d_out, int out_size, void* d_ws, size_t ws_size,
                              hipStream_t stream) {
  const float* x   = (const float*)d_in[0];
  const int* ei    = (const int*)d_in[1];
  const int* batch = (const int*)d_in[2];
  const float* W1  = (const float*)d_in[3];
  const float* as1 = (const float*)d_in[4];
  const float* ad1 = (const float*)d_in[5];
  const float* b1  = (const float*)d_in[6];
  const float* W2  = (const float*)d_in[7];
  const float* as2 = (const float*)d_in[8];
  const float* ad2 = (const float*)d_in[9];
  const float* b2  = (const float*)d_in[10];

  float* out_feats = (float*)d_out;
  float* pooled    = out_feats + (size_t)NN * DIM;

  const int* src = ei;
  const int* dst = ei + NE;

  char* w = (char*)d_ws;
  uint32* h16 = (uint32*)w;   w += pad256((size_t)NN * 64 * 4);    // bf16-packed h (12.8 MB)
  uint32* f116 = (uint32*)w;  w += pad256((size_t)NN * 64 * 4);    // bf16-packed layer-1 out
  float* alpha_s = (float*)w; w += pad256((size_t)NN * 4);
  float* alpha_d = (float*)w; w += pad256((size_t)NN * 4);
  int* deg  = (int*)w;        w += pad256((size_t)NN * 4);
  int* offs = (int*)w;        w += pad256((size_t)(NN + 1) * 4);
  int* fill = (int*)w;        w += pad256((size_t)NN * 4);
  int* csr  = (int*)w;        w += pad256((size_t)ETOT * 4);
  float* cnt  = (float*)w;    w += pad256((size_t)NG * 4);
  int* bsum = (int*)w;        w += pad256((size_t)NB_SCAN * 4);
  int* bpre = (int*)w;        w += pad256((size_t)NB_SCAN * 4);
  ushort* wt1 = (ushort*)w;   w += pad256((size_t)DIM * DIM * 2);
  ushort* wt2 = (ushort*)w;   w += pad256((size_t)DIM * DIM * 2);

  const int NB_N = (NN + 255) / 256;
  const int NB_E = (NE + 255) / 256;
  const int NB_A = (NN + 63) / 64;              // 782 staged-aggregation blocks
  const int NB_G = (NN + 63) / 64;
  const int NB_SC = 1024;                       // sharded scatter: 128 blocks x 8 shards

  // CSR build + weight prep (graph shared by both layers)
  k_init<<<NB_N, 256, 0, stream>>>(W1, W2, wt1, wt2, deg, fill, pooled, cnt);
  k_count<<<NB_E, 256, 0, stream>>>(dst, deg);
  k_scan1<<<NB_SCAN, 256, 0, stream>>>(deg, offs, bsum);
  k_scan2<<<1, 256, 0, stream>>>(bsum, bpre);
  k_scan3<<<NB_SCAN, 256, 0, stream>>>(offs, bpre, deg, csr);   // + self-loop placement
  k_scatter<<<NB_SC, 256, 0, stream>>>(src, dst, offs, fill, csr);

  // layer 1
  k_mm<0><<<NB_G, 256, 0, stream>>>(x, wt1, as1, ad1, h16, alpha_s, alpha_d, NN);
  k_sma<1><<<NB_A, 256, 0, stream>>>(offs, csr, alpha_s, alpha_d, h16, b1, nullptr, f116);

  // layer 2
  k_mm<1><<<NB_G, 256, 0, stream>>>(f116, wt2, as2, ad2, h16, alpha_s, alpha_d, NN);
  k_sma<0><<<NB_A, 256, 0, stream>>>(offs, csr, alpha_s, alpha_d, h16, b2, out_feats, nullptr);

  // pool
  k_pool_partial<<<PB, 256, 0, stream>>>(out_feats, batch, pooled, cnt);
  k_pool_norm<<<(NG * DIM + 255) / 256, 256, 0, stream>>>(pooled, cnt);
}

// Round 10
// 223.920 us; speedup vs baseline: 1.1077x; 1.1077x over previous
//
#include <hip/hip_runtime.h>

#define NN 50000
#define NE 800000
#define DIM 128
#define NG 64
#define ETOT (NE + NN)
#define NEG_SLOPE 0.2f
#define PB 200          // pooling blocks; chunk = 250 nodes
#define MAXLG 8         // local graph slots per block
#define NSH 8           // dst shards (== XCDs)
#define SHW ((NN + NSH - 1) / NSH)   // 6250 nodes per shard
#define NB_SCAN ((NN + 255) / 256)   // 196
#define CAP 512         // staged edges per 4-node block (mean 68; P(>512) ~ 0)

typedef unsigned int uint32;
typedef unsigned short ushort;
typedef short bf16x8 __attribute__((ext_vector_type(8)));
typedef float f32x4 __attribute__((ext_vector_type(4)));

static __device__ __forceinline__ uint32 f2bf_pack(float lo, float hi) {
  uint32 a = __float_as_uint(lo), b = __float_as_uint(hi);
  a = (a + 0x7fffu + ((a >> 16) & 1u)) >> 16;          // RNE
  b = (b + 0x7fffu + ((b >> 16) & 1u)) >> 16;
  return a | (b << 16);
}
static __device__ __forceinline__ ushort f2bf1(float x) {
  uint32 a = __float_as_uint(x);
  a = (a + 0x7fffu + ((a >> 16) & 1u)) >> 16;
  return (ushort)a;
}
static __device__ __forceinline__ float bf_lo(uint32 u) { return __uint_as_float(u << 16); }
static __device__ __forceinline__ float bf_hi(uint32 u) { return __uint_as_float(u & 0xffff0000u); }

// ============================ init + weight prep (fused) ============================

__global__ __launch_bounds__(256) void k_init(const float* __restrict__ W1, const float* __restrict__ W2,
                                              ushort* __restrict__ wt1, ushort* __restrict__ wt2,
                                              int* deg, int* fill, float* pooled, float* cnt) {
  int i = blockIdx.x * 256 + threadIdx.x;
  if (i < NN) { deg[i] = 1; fill[i] = 1; }          // 1 = self-loop
  if (i < NG * DIM) pooled[i] = 0.f;
  if (i < NG) cnt[i] = 0.f;
  if (i < DIM * DIM) {                              // W^T bf16 rows (contiguous k) for MFMA B-frags
    int n = i >> 7, k = i & 127;
    wt1[i] = f2bf1(W1[k * DIM + n]);
    wt2[i] = f2bf1(W2[k * DIM + n]);
  }
}

__global__ __launch_bounds__(256) void k_count(const int* __restrict__ dst, int* __restrict__ deg) {
  int e = blockIdx.x * 256 + threadIdx.x;
  if (e < NE) atomicAdd(&deg[dst[e]], 1);
}

// ---- 3-phase multi-block inclusive scan: offs[i+1] = sum(deg[0..i]) ----

__global__ __launch_bounds__(256) void k_scan1(const int* __restrict__ deg, int* __restrict__ offs,
                                               int* __restrict__ bsum) {
  __shared__ int ws[4];
  const int i = blockIdx.x * 256 + threadIdx.x;
  const int lane = threadIdx.x & 63, wid = threadIdx.x >> 6;
  int x = (i < NN) ? deg[i] : 0;
#pragma unroll
  for (int off = 1; off < 64; off <<= 1) {
    int t = __shfl_up(x, off, 64);
    if (lane >= off) x += t;
  }
  if (lane == 63) ws[wid] = x;
  __syncthreads();
  int pre = 0;
#pragma unroll
  for (int j = 0; j < 3; ++j) if (j < wid) pre += ws[j];
  x += pre;
  if (i < NN) offs[i + 1] = x;
  if (threadIdx.x == 255) bsum[blockIdx.x] = x;
}

__global__ __launch_bounds__(256) void k_scan2(const int* __restrict__ bsum, int* __restrict__ bpre) {
  __shared__ int ws[4];
  const int b = threadIdx.x;
  const int lane = b & 63, wid = b >> 6;
  int v = (b < NB_SCAN) ? bsum[b] : 0;
  int x = v;
#pragma unroll
  for (int off = 1; off < 64; off <<= 1) {
    int t = __shfl_up(x, off, 64);
    if (lane >= off) x += t;
  }
  if (lane == 63) ws[wid] = x;
  __syncthreads();
  int pre = 0;
#pragma unroll
  for (int j = 0; j < 3; ++j) if (j < wid) pre += ws[j];
  x += pre;
  if (b < NB_SCAN) bpre[b] = x - v;     // exclusive prefix of block totals
}

// scan3 + self-loop placement fused: slot offs[i] == offs[i+1] - deg[i]
__global__ __launch_bounds__(256) void k_scan3(int* __restrict__ offs, const int* __restrict__ bpre,
                                               const int* __restrict__ deg, int* __restrict__ csr) {
  const int i = blockIdx.x * 256 + threadIdx.x;
  if (i < NN) {
    int v = offs[i + 1] + bpre[blockIdx.x];
    offs[i + 1] = v;
    csr[v - deg[i]] = i;                // slot 0 of each segment = self-loop
  }
  if (i == 0) offs[0] = 0;
}

// XCD-sharded scatter (round-5 notes): each csr line dirtied by one XCD only.
__global__ __launch_bounds__(256) void k_scatter(const int* __restrict__ src, const int* __restrict__ dst,
                                                 const int* __restrict__ offs, int* __restrict__ fill,
                                                 int* __restrict__ csr) {
  const int r = blockIdx.x & (NSH - 1);
  const int bi = blockIdx.x >> 3;
  const int nb = gridDim.x >> 3;
  const int lo = r * SHW, hi = min(lo + SHW, NN);
  for (int e = bi * 256 + threadIdx.x; e < NE; e += nb * 256) {
    int d = dst[e];
    if (d >= lo && d < hi) {
      int p = offs[d] + atomicAdd(&fill[d], 1);
      csr[p] = src[e];
    }
  }
}

// ============== MFMA GEMM: H16 = bf16(X @ W), alpha fused; A16=1 -> X is bf16-packed ==============

template <int A16>
__global__ __launch_bounds__(256) void k_mm(const void* __restrict__ Xv, const ushort* __restrict__ WT,
                                            const float* __restrict__ a_s, const float* __restrict__ a_d,
                                            uint32* __restrict__ H16,
                                            float* __restrict__ alpha_s, float* __restrict__ alpha_d, int n) {
  __shared__ __align__(16) ushort sWT[DIM * DIM];   // 32 KB
  __shared__ __align__(16) ushort sA[64 * DIM];     // 16 KB
  const int tid = threadIdx.x;
  const int row0 = blockIdx.x * 64;

  {  // stage W^T -> LDS (swizzled)
    const int nr = tid >> 1, h2 = tid & 1;
    const uint4* wp = (const uint4*)(WT + nr * DIM + h2 * 64);
#pragma unroll
    for (int i = 0; i < 8; ++i) {
      uint4 v = wp[i];
      int byte = nr * 256 + (((h2 * 128 + i * 16)) ^ ((nr & 7) << 4));
      *(uint4*)((char*)sWT + byte) = v;
    }
  }
  {  // stage A -> LDS (bf16, swizzled)
    const int r = tid >> 2, q = tid & 3;
    int rg = row0 + r; if (rg > n - 1) rg = n - 1;
    if (A16) {
      const uint4* xp = (const uint4*)((const uint32*)Xv + (size_t)rg * 64 + q * 16);
#pragma unroll
      for (int i = 0; i < 4; ++i) {
        uint4 pk = xp[i];
        int byte = r * 256 + ((q * 64 + i * 16) ^ ((r & 7) << 4));
        *(uint4*)((char*)sA + byte) = pk;
      }
    } else {
      const float4* xp = (const float4*)((const float*)Xv + (size_t)rg * DIM + q * 32);
#pragma unroll
      for (int i = 0; i < 4; ++i) {
        float4 v0 = xp[2 * i], v1 = xp[2 * i + 1];
        uint4 pk = make_uint4(f2bf_pack(v0.x, v0.y), f2bf_pack(v0.z, v0.w),
                              f2bf_pack(v1.x, v1.y), f2bf_pack(v1.z, v1.w));
        int byte = r * 256 + ((q * 64 + i * 16) ^ ((r & 7) << 4));
        *(uint4*)((char*)sA + byte) = pk;
      }
    }
  }
  __syncthreads();

  const int l = tid & 63, wv = tid >> 6;
  const int jr = l & 15, g = l >> 4;
  const int m0 = wv * 16;
  f32x4 acc[8];
#pragma unroll
  for (int nt = 0; nt < 8; ++nt) acc[nt] = (f32x4){0.f, 0.f, 0.f, 0.f};

  const int ra = m0 + jr;
  const int abase = ra * 256, aswz = (ra & 7) << 4;
  const int bswz = (jr & 7) << 4;
#pragma unroll
  for (int kk = 0; kk < 4; ++kk) {
    const int kb = kk * 64 + g * 16;
    bf16x8 af = *(const bf16x8*)((const char*)sA + abase + (kb ^ aswz));
#pragma unroll
    for (int nt = 0; nt < 8; ++nt) {
      bf16x8 bfg = *(const bf16x8*)((const char*)sWT + (nt * 16 + jr) * 256 + (kb ^ bswz));
      acc[nt] = __builtin_amdgcn_mfma_f32_16x16x32_bf16(af, bfg, acc[nt], 0, 0, 0);
    }
  }

  // fused alpha from f32 accumulators: row = m0 + g*4 + j, col = nt*16 + jr
  float asv[8], adv[8];
#pragma unroll
  for (int nt = 0; nt < 8; ++nt) { asv[nt] = a_s[nt * 16 + jr]; adv[nt] = a_d[nt * 16 + jr]; }
#pragma unroll
  for (int j = 0; j < 4; ++j) {
    float ps = 0.f, pd = 0.f;
#pragma unroll
    for (int nt = 0; nt < 8; ++nt) {
      ps = fmaf(acc[nt][j], asv[nt], ps);
      pd = fmaf(acc[nt][j], adv[nt], pd);
    }
#pragma unroll
    for (int off = 1; off < 16; off <<= 1) {
      ps += __shfl_xor(ps, off, 64);
      pd += __shfl_xor(pd, off, 64);
    }
    int r = row0 + m0 + g * 4 + j;
    if (jr == 0 && r < n) { alpha_s[r] = ps; alpha_d[r] = pd; }
  }

  // bf16 output bounce through this wave's own sA rows, then coalesced stores
  ushort* sOut = sA;
#pragma unroll
  for (int nt = 0; nt < 8; ++nt)
#pragma unroll
    for (int j = 0; j < 4; ++j)
      sOut[(m0 + g * 4 + j) * DIM + nt * 16 + jr] = f2bf1(acc[nt][j]);
#pragma unroll
  for (int i = 0; i < 4; ++i) {
    int r = row0 + m0 + (l >> 4) + i * 4;
    uint4 v = *(const uint4*)((const char*)sOut + m0 * 256 + l * 16 + i * 1024);
    if (r < n) *(uint4*)(H16 + (size_t)(row0 + m0) * 64 + l * 4 + i * 256) = v;
  }
}

// ============ fused edge-softmax + aggregation v4: LDS-staged, 4 nodes/block, 1 wave/node ============
// Phase 1 (all 256 threads): stage (src, alpha_s[src]) pairs for the block's ~68 edges
//   (coalesced csr read + high-ILP alpha gather). One barrier.
// Phase 2 (per wave, independent): softmax over own node's staged pairs (ex overwrites
//   alpha in place -- own-wave LDS writes, no barrier), then gather: per edge one uniform
//   ds_read_b64 of (src, ex) + one 256B feature row load + 2 fma. No ds_bpermute, no
//   lockstep, 50000 waves for latency hiding.

template <int STORE16>
__global__ __launch_bounds__(256) void k_sma(const int* __restrict__ offs, const int* __restrict__ csr,
                                             const float* __restrict__ alpha_s, const float* __restrict__ alpha_d,
                                             const uint32* __restrict__ H16, const float* __restrict__ bias,
                                             float* __restrict__ out, uint32* __restrict__ out16) {
  __shared__ int2 s_pair[CAP];          // (src, alpha|ex)
  __shared__ int s_off[5];
  const int tid = threadIdx.x;
  const int n0 = blockIdx.x * 4;
  if (tid <= 4) s_off[tid] = offs[n0 + tid];
  __syncthreads();
  const int ebeg = s_off[0];
  const int nE = s_off[4] - ebeg;
  const int l = tid & 63, wv = tid >> 6;
  const int node = n0 + wv;
  const float2 bb = *(const float2*)(bias + 2 * l);
  float ax = 0.f, ay = 0.f, inv;

  if (nE <= CAP) {
    // ---- phase 1: stage ----
    for (int e = tid; e < nE; e += 256) {
      int sv = csr[ebeg + e];
      s_pair[e] = make_int2(sv, __float_as_int(alpha_s[sv]));
    }
    __syncthreads();
    // ---- phase 2: per-wave softmax (own range) + gather ----
    const int jb = s_off[wv] - ebeg, je = s_off[wv + 1] - ebeg;
    const float ad = alpha_d[node];
    float m = -1e30f;
    for (int j = jb + l; j < je; j += 64) {
      float sc = __int_as_float(s_pair[j].y) + ad;
      sc = sc > 0.f ? sc : NEG_SLOPE * sc;
      m = fmaxf(m, sc);
    }
#pragma unroll
    for (int off = 1; off < 64; off <<= 1) m = fmaxf(m, __shfl_xor(m, off, 64));
    float ssum = 0.f;
    for (int j = jb + l; j < je; j += 64) {
      float sc = __int_as_float(s_pair[j].y) + ad;
      sc = sc > 0.f ? sc : NEG_SLOPE * sc;
      float ex = __expf(sc - m);
      s_pair[j].y = __float_as_int(ex);
      ssum += ex;
    }
#pragma unroll
    for (int off = 1; off < 64; off <<= 1) ssum += __shfl_xor(ssum, off, 64);
    inv = 1.f / (ssum + 1e-16f);

    int j = jb;
    for (; j + 3 < je; j += 4) {
      int2 p0 = s_pair[j], p1 = s_pair[j + 1], p2 = s_pair[j + 2], p3 = s_pair[j + 3];
      uint32 v0 = H16[(size_t)p0.x * 64 + l];
      uint32 v1 = H16[(size_t)p1.x * 64 + l];
      uint32 v2 = H16[(size_t)p2.x * 64 + l];
      uint32 v3 = H16[(size_t)p3.x * 64 + l];
      float c0 = __int_as_float(p0.y), c1 = __int_as_float(p1.y);
      float c2 = __int_as_float(p2.y), c3 = __int_as_float(p3.y);
      ax = fmaf(c0, bf_lo(v0), ax); ay = fmaf(c0, bf_hi(v0), ay);
      ax = fmaf(c1, bf_lo(v1), ax); ay = fmaf(c1, bf_hi(v1), ay);
      ax = fmaf(c2, bf_lo(v2), ax); ay = fmaf(c2, bf_hi(v2), ay);
      ax = fmaf(c3, bf_lo(v3), ax); ay = fmaf(c3, bf_hi(v3), ay);
    }
    for (; j < je; ++j) {
      int2 p0 = s_pair[j];
      uint32 v0 = H16[(size_t)p0.x * 64 + l];
      float c0 = __int_as_float(p0.y);
      ax = fmaf(c0, bf_lo(v0), ax); ay = fmaf(c0, bf_hi(v0), ay);
    }
  } else {
    // ---- fallback: direct per-node two-pass from global (nE > CAP; essentially never) ----
    const int bg = offs[node], eg = offs[node + 1];
    const float ad = alpha_d[node];
    float m = -1e30f;
    for (int jj = bg + l; jj < eg; jj += 64) {
      float sc = alpha_s[csr[jj]] + ad;
      sc = sc > 0.f ? sc : NEG_SLOPE * sc;
      m = fmaxf(m, sc);
    }
#pragma unroll
    for (int off = 1; off < 64; off <<= 1) m = fmaxf(m, __shfl_xor(m, off, 64));
    float ssum = 0.f;
    for (int base = bg; base < eg; base += 64) {
      int cnt = min(64, eg - base);
      int sv = 0; float ex = 0.f;
      if (l < cnt) {
        sv = csr[base + l];
        float sc = alpha_s[sv] + ad;
        sc = sc > 0.f ? sc : NEG_SLOPE * sc;
        ex = __expf(sc - m);
      }
      ssum += ex;
      for (int jj = 0; jj < cnt; ++jj) {
        int s0 = __shfl(sv, jj, 64); float c0 = __shfl(ex, jj, 64);
        uint32 v0 = H16[(size_t)s0 * 64 + l];
        ax = fmaf(c0, bf_lo(v0), ax); ay = fmaf(c0, bf_hi(v0), ay);
      }
    }
#pragma unroll
    for (int off = 1; off < 64; off <<= 1) ssum += __shfl_xor(ssum, off, 64);
    inv = 1.f / (ssum + 1e-16f);
  }

  const float ox = ax * inv + bb.x, oy = ay * inv + bb.y;
  if (STORE16) out16[(size_t)node * 64 + l] = f2bf_pack(ox, oy);
  else *(float2*)(out + (size_t)node * DIM + 2 * l) = make_float2(ox, oy);
}

// ============================ global mean pool (hierarchical, batch sorted) ============================

__global__ __launch_bounds__(256) void k_pool_partial(const float* __restrict__ feats,
                                                      const int* __restrict__ batch,
                                                      float* __restrict__ pooled, float* __restrict__ cnt) {
  __shared__ float acc[4][MAXLG][DIM];
  __shared__ float lcnt[4][MAXLG];
  const int tid = threadIdx.x;
  const int wid = tid >> 6, l = tid & 63;
  for (int i = tid; i < 4 * MAXLG * DIM; i += 256) ((float*)acc)[i] = 0.f;
  if (tid < 4 * MAXLG) ((float*)lcnt)[tid] = 0.f;
  __syncthreads();

  const int chunk = (NN + PB - 1) / PB;
  const int beg = blockIdx.x * chunk;
  const int end = min(beg + chunk, NN);
  const int g0 = (beg < NN) ? batch[beg] : 0;

  for (int node = beg + wid; node < end; node += 4) {
    int lg = batch[node] - g0;
    float2 v = *(const float2*)(feats + (size_t)node * DIM + 2 * l);
    if (lg < MAXLG) {
      acc[wid][lg][2 * l] += v.x;
      acc[wid][lg][2 * l + 1] += v.y;
      if (l == 0) lcnt[wid][lg] += 1.f;
    } else {
      atomicAdd(&pooled[(g0 + lg) * DIM + 2 * l], v.x);
      atomicAdd(&pooled[(g0 + lg) * DIM + 2 * l + 1], v.y);
      if (l == 0) atomicAdd(&cnt[g0 + lg], 1.f);
    }
  }
  __syncthreads();

  for (int i = tid; i < MAXLG * DIM; i += 256) {
    int lg = i >> 7, d = i & (DIM - 1);
    float s = acc[0][lg][d] + acc[1][lg][d] + acc[2][lg][d] + acc[3][lg][d];
    if (s != 0.f) atomicAdd(&pooled[(g0 + lg) * DIM + d], s);
  }
  if (tid < MAXLG) {
    float s = lcnt[0][tid] + lcnt[1][tid] + lcnt[2][tid] + lcnt[3][tid];
    if (s != 0.f) atomicAdd(&cnt[g0 + tid], s);
  }
}

__global__ __launch_bounds__(256) void k_pool_norm(float* pooled, const float* __restrict__ cnt) {
  int i = blockIdx.x * 256 + threadIdx.x;
  if (i < NG * DIM) pooled[i] /= fmaxf(cnt[i >> 7], 1.f);
}

// ============================ launch ============================

static inline size_t pad256(size_t x) { return (x + 255) & ~(size_t)255; }

extern "C" void kernel_launch(void* const* d_in, const int* in_sizes, int n_in,
                              void* d_out, int out_size, void* d_ws, size_t ws_size,
                              hipStream_t stream) {
  const float* x   = (const float*)d_in[0];
  const int* ei    = (const int*)d_in[1];
  const int* batch = (const int*)d_in[2];
  const float* W1  = (const float*)d_in[3];
  const float* as1 = (const float*)d_in[4];
  const float* ad1 = (const float*)d_in[5];
  const float* b1  = (const float*)d_in[6];
  const float* W2  = (const float*)d_in[7];
  const float* as2 = (const float*)d_in[8];
  const float* ad2 = (const float*)d_in[9];
  const float* b2  = (const float*)d_in[10];

  float* out_feats = (float*)d_out;
  float* pooled    = out_feats + (size_t)NN * DIM;

  const int* src = ei;
  const int* dst = ei + NE;

  char* w = (char*)d_ws;
  uint32* h16 = (uint32*)w;   w += pad256((size_t)NN * 64 * 4);    // bf16-packed h (12.8 MB)
  uint32* f116 = (uint32*)w;  w += pad256((size_t)NN * 64 * 4);    // bf16-packed layer-1 out
  float* alpha_s = (float*)w; w += pad256((size_t)NN * 4);
  float* alpha_d = (float*)w; w += pad256((size_t)NN * 4);
  int* deg  = (int*)w;        w += pad256((size_t)NN * 4);
  int* offs = (int*)w;        w += pad256((size_t)(NN + 1) * 4);
  int* fill = (int*)w;        w += pad256((size_t)NN * 4);
  int* csr  = (int*)w;        w += pad256((size_t)ETOT * 4);
  float* cnt  = (float*)w;    w += pad256((size_t)NG * 4);
  int* bsum = (int*)w;        w += pad256((size_t)NB_SCAN * 4);
  int* bpre = (int*)w;        w += pad256((size_t)NB_SCAN * 4);
  ushort* wt1 = (ushort*)w;   w += pad256((size_t)DIM * DIM * 2);
  ushort* wt2 = (ushort*)w;   w += pad256((size_t)DIM * DIM * 2);

  const int NB_N = (NN + 255) / 256;
  const int NB_E = (NE + 255) / 256;
  const int NB_A = NN / 4;                      // 12500 blocks, 1 wave per node
  const int NB_G = (NN + 63) / 64;
  const int NB_SC = 1024;                       // sharded scatter: 128 blocks x 8 shards

  // CSR build + weight prep (graph shared by both layers)
  k_init<<<NB_N, 256, 0, stream>>>(W1, W2, wt1, wt2, deg, fill, pooled, cnt);
  k_count<<<NB_E, 256, 0, stream>>>(dst, deg);
  k_scan1<<<NB_SCAN, 256, 0, stream>>>(deg, offs, bsum);
  k_scan2<<<1, 256, 0, stream>>>(bsum, bpre);
  k_scan3<<<NB_SCAN, 256, 0, stream>>>(offs, bpre, deg, csr);   // + self-loop placement
  k_scatter<<<NB_SC, 256, 0, stream>>>(src, dst, offs, fill, csr);

  // layer 1
  k_mm<0><<<NB_G, 256, 0, stream>>>(x, wt1, as1, ad1, h16, alpha_s, alpha_d, NN);
  k_sma<1><<<NB_A, 256, 0, stream>>>(offs, csr, alpha_s, alpha_d, h16, b1, nullptr, f116);

  // layer 2
  k_mm<1><<<NB_G, 256, 0, stream>>>(f116, wt2, as2, ad2, h16, alpha_s, alpha_d, NN);
  k_sma<0><<<NB_A, 256, 0, stream>>>(offs, csr, alpha_s, alpha_d, h16, b2, out_feats, nullptr);

  // pool
  k_pool_partial<<<PB, 256, 0, stream>>>(out_feats, batch, pooled, cnt);
  k_pool_norm<<<(NG * DIM + 255) / 256, 256, 0, stream>>>(pooled, cnt);
}